// Round 3
// baseline (76928.925 us; speedup 1.0000x reference)
//
#include <hip/hip_runtime.h>
#include <cstdint>

// Reference semantics (validated, absmax=0.0 — DO NOT change arithmetic):
//  - selection on RAW f32 coords, distance = fma(dz,dz, fma(dx,dx, dy*dy))
//    with dx/dy/dz plain f32 subs;
//  - min/argmax exact, FIRST-index tie-break (min global point index);
//  - output coords bf16-RNE-rounded, batch = float b.
//
// R14 structural change: R11-R13 all ~8.2ms with one CU per cloud (16/256 CUs
// busy, ~78% VALU on active CUs). NOTE: FETCH/WRITE are KB — no scratch leak
// ever existed; single-CU serial structure is the wall. Now 8 blocks per
// cloud (128 blocks): per-iter argmax exchanged via device-scope tag/key
// protocol in d_ws:
//   key  = (f32_bits(maxdist) << 32) | ~(u32)global_idx   (max == reference
//          argmax with first-index tie-break; dists >= 0 so f32 bits monotone)
//   slot = [cloud][j&1][r]; writer: relaxed key store, release tag=j store;
//   readers: acquire-poll tag==j then relaxed key load.
// Parity-doubling is sufficient: block A reaches publish(j+2) only after all
// blocks passed poll(j+1), which requires all passed poll(j), i.e. everyone
// has consumed A's slot-j value before it is overwritten. Tags zeroed per
// call by hipMemsetAsync (stream-ordered, graph-capturable).
// blockIdx = r*16 + b => all 8 blocks of cloud b land on XCD b%8 (round-robin
// heuristic; correctness is scope-based, placement only helps L2 locality).
#pragma clang fp contract(off)

#define B_ 16
#define N_ 16384
#define K_ 4096
#define G_ 8                    // blocks per cloud
#define T_ 512                  // threads per block
#define PPB_ (N_ / G_)          // 2048 points per block
#define PT_ (PPB_ / T_)         // 4 points per thread
#define NW_ (T_ / 64)           // 8 waves per block

#define PTS_LIST(X) X(0) X(1) X(2) X(3)

// f32 -> bf16 RNE, returned as the bf16-representable f32 (finite inputs)
__device__ __forceinline__ float bfr(float f) {
  union { float f; uint32_t i; } c; c.f = f;
  c.i = (c.i + 0x7FFFu + ((c.i >> 16) & 1u)) & 0xFFFF0000u;
  return c.f;
}

__device__ __forceinline__ unsigned long long shfl_xor_u64(unsigned long long v, int m) {
  const int lo = __shfl_xor((int)(unsigned)v, m, 64);
  const int hi = __shfl_xor((int)(unsigned)(v >> 32), m, 64);
  return ((unsigned long long)(unsigned)hi << 32) | (unsigned)lo;
}

__global__ __launch_bounds__(T_)
void fps_kernel(const float* __restrict__ x, float* __restrict__ out,
                unsigned long long* __restrict__ wkeys,
                unsigned* __restrict__ wtags)
{
#pragma clang fp contract(off)
  const int bid  = blockIdx.x;
  const int b    = bid & 15;      // cloud id   (bid = r*16 + b)
  const int r    = bid >> 4;      // sub-block  [0, G_)
  const int t    = threadIdx.x;
  const int lane = t & 63;
  const int wave = t >> 6;

  // parity-double-buffered per-wave argmax partials (one barrier/iter)
  __shared__ float s_v[2][NW_];
  __shared__ int   s_g[2][NW_];

  const float* xb  = x + (size_t)b * (N_ * 3);
  float* out_x     = out;                        // [B*K*3] f32 (bf16-grid values)
  float* out_batch = out + (size_t)B_ * K_ * 3;  // [B*K]   f32 cloud ids

  // batch output: 8 blocks x 512 threads = 4096 = K entries, one each
  out_batch[b * K_ + r * T_ + t] = (float)b;

  // this block owns cloud points [r*PPB_, (r+1)*PPB_); thread t slot i owns
  // cloud-local index r*PPB_ + i*T_ + t
#define DECLP(i) float px##i, py##i, pz##i, m##i;
  PTS_LIST(DECLP)
#undef DECLP

#define LOADP(i) { const float* p_ = xb + 3 * (r * PPB_ + (i) * T_ + t); \
                   px##i = p_[0]; py##i = p_[1]; pz##i = p_[2];          \
                   m##i = __builtin_inff(); }
  PTS_LIST(LOADP)
#undef LOADP

  // Per-point update + fused local argmax (bit-exact FMA-V1 distance)
#define UPD(i) { const float dx_ = px##i - cx;                                  \
                 const float dy_ = py##i - cy;                                  \
                 const float dz_ = pz##i - cz;                                  \
                 const float d_  = __builtin_fmaf(dz_, dz_,                     \
                                   __builtin_fmaf(dx_, dx_, dy_ * dy_));        \
                 m##i = fminf(m##i, d_);                                        \
                 if (m##i > bv) { bv = m##i; bs = (i); } }

  // ---- iteration 0: seed = point 0 (known to every block, no sync) ----
  float cx = xb[0], cy = xb[1], cz = xb[2];
  if (r == 0 && t == 0) {
    const uint64_t o = ((uint64_t)b * K_) * 3;
    out_x[o + 0] = bfr(cx); out_x[o + 1] = bfr(cy); out_x[o + 2] = bfr(cz);
  }

  float bv = -1.0f; int bs = 0;
  PTS_LIST(UPD)                       // ascending i scan keeps first index
  int bg = r * PPB_ + bs * T_ + t;    // cloud-global point index
#pragma unroll
  for (int m = 32; m >= 1; m >>= 1) {
    const float ov = __shfl_xor(bv, m, 64);
    const int   og = __shfl_xor(bg, m, 64);
    if (ov > bv || (ov == bv && og < bg)) { bv = ov; bg = og; }
  }
  if (lane == 0) { s_v[0][wave] = bv; s_g[0][wave] = bg; }
  __syncthreads();

  // ---- iterations 1..K-1 ----
  for (int j = 1; j < K_; ++j) {
    const int rp = (j - 1) & 1;   // partials parity to read
    const int wp = j & 1;         // partials parity to write at end
    const int sp = j & 1;         // global slot parity for this iteration

    // block candidate: every lane reads slot lane&7, 3-level butterfly
    // (max with min-index tie-break is associative -> same winner as scan)
    float v = s_v[rp][lane & 7];
    int   g = s_g[rp][lane & 7];
#pragma unroll
    for (int m = 4; m >= 1; m >>= 1) {
      const float ov = __shfl_xor(v, m, 64);
      const int   og = __shfl_xor(g, m, 64);
      if (ov > v || (ov == v && og < g)) { v = ov; g = og; }
    }

    unsigned long long* kslot = wkeys + (((b << 1) | sp) << 3);  // [b][sp][8]
    unsigned*           tslot = wtags + (((b << 1) | sp) << 3);

    if (t == 0) {
      union { float f; unsigned u; } cv; cv.f = v;
      const unsigned long long key =
          ((unsigned long long)cv.u << 32) | (unsigned)(~(unsigned)g);
      __hip_atomic_store(&kslot[r], key, __ATOMIC_RELAXED, __HIP_MEMORY_SCOPE_AGENT);
      __hip_atomic_store(&tslot[r], (unsigned)j, __ATOMIC_RELEASE, __HIP_MEMORY_SCOPE_AGENT);
    }

    // poll the 8 sub-block slots (lane q = lane&7 watches slot q; all waves
    // poll independently -> no second intra-block barrier needed)
    const int q = lane & 7;
    unsigned tg;
    do {
      tg = __hip_atomic_load(&tslot[q], __ATOMIC_ACQUIRE, __HIP_MEMORY_SCOPE_AGENT);
    } while (tg != (unsigned)j);
    unsigned long long key =
        __hip_atomic_load(&kslot[q], __ATOMIC_RELAXED, __HIP_MEMORY_SCOPE_AGENT);
#pragma unroll
    for (int m = 4; m >= 1; m >>= 1) {
      const unsigned long long ok = shfl_xor_u64(key, m);
      if (ok > key) key = ok;
    }
    const int gg = (int)(~(unsigned)key);   // winner cloud-global index
    const int gu = __builtin_amdgcn_readfirstlane(gg);

    // uniform broadcast load of the chosen point's raw coords
    cx = xb[3 * gu + 0];
    cy = xb[3 * gu + 1];
    cz = xb[3 * gu + 2];
    if (r == 0 && t == 0) {
      const uint64_t o = ((uint64_t)b * K_ + j) * 3;
      out_x[o + 0] = bfr(cx); out_x[o + 1] = bfr(cy); out_x[o + 2] = bfr(cz);
    }

    // update mind + fused local argmax for next round
    bv = -1.0f; bs = 0;
    PTS_LIST(UPD)
    bg = r * PPB_ + bs * T_ + t;
#pragma unroll
    for (int m = 32; m >= 1; m >>= 1) {
      const float ov = __shfl_xor(bv, m, 64);
      const int   og = __shfl_xor(bg, m, 64);
      if (ov > bv || (ov == bv && og < bg)) { bv = ov; bg = og; }
    }
    if (lane == 0) { s_v[wp][wave] = bv; s_g[wp][wave] = bg; }
    __syncthreads();
  }
#undef UPD
}

extern "C" void kernel_launch(void* const* d_in, const int* in_sizes, int n_in,
                              void* d_out, int out_size, void* d_ws, size_t ws_size,
                              hipStream_t stream) {
  const float* x = (const float*)d_in[0];  // f32, [B*N, 3]
  float* out     = (float*)d_out;          // f32: [B*K*3] coords + [B*K] batch
  (void)in_sizes; (void)n_in; (void)out_size; (void)ws_size;

  unsigned long long* wkeys = (unsigned long long*)d_ws;
  unsigned* wtags = (unsigned*)((char*)d_ws + (size_t)B_ * 2 * G_ * sizeof(unsigned long long));
  const size_t sync_bytes = (size_t)B_ * 2 * G_ * (sizeof(unsigned long long) + sizeof(unsigned));

  // zero the tag/key region every call (stream-ordered; graph-capturable)
  hipMemsetAsync(d_ws, 0, sync_bytes, stream);
  hipLaunchKernelGGL(fps_kernel, dim3(B_ * G_), dim3(T_), 0, stream, x, out, wkeys, wtags);
}

// Round 4
// 5826.708 us; speedup vs baseline: 13.2028x; 13.2028x over previous
//
#include <hip/hip_runtime.h>
#include <cstdint>

// Reference semantics (validated, absmax=0.0 — DO NOT change arithmetic):
//  - selection on RAW f32 coords, distance = fma(dz,dz, fma(dx,dx, dy*dy))
//    with dx/dy/dz plain f32 subs;
//  - min/argmax exact, FIRST-index tie-break (min global point index);
//  - output coords bf16-RNE-rounded, batch = float b.
//
// R15 theory: R11-R13 all ~8.2ms because the compiler REMATERIALIZES the
// loop-invariant point loads (VGPR_Count=52 proves points were never
// register-resident) -> every thread re-streams 48 coord dwords from L1/L2
// per iteration (~3000-4000 cyc VMEM per iter). R14 proved cross-block sync
// costs ~19us/iter -> single CU per cloud is mandatory.
// Fixes:
//  1) asm-pin every point register after load (zero-instr anti-remat fence);
//     live set ~85 VGPR < 128 budget at the mandatory 4 waves/SIMD.
//  2) packed u64 key (f32bits<<32 | ~idx, same lattice as validated R14) +
//     DPP butterfly (quad_perm xor1/xor2, row_half_mirror=xor7,
//     row_mirror=xor15 -> pure VALU) with __shfl_xor only at 16/32;
//     finalize = 1x ds_read_b64 + 4 DPP levels (zero bpermute).
#pragma clang fp contract(off)

#define B_ 16
#define N_ 16384
#define K_ 4096
#define THREADS_ 1024
#define PTS_ (N_ / THREADS_)   // 16 points per thread
#define NW_ (THREADS_ / 64)    // 16 waves per block

#define PTS_LIST(X) \
  X(0) X(1) X(2) X(3) X(4) X(5) X(6) X(7) \
  X(8) X(9) X(10) X(11) X(12) X(13) X(14) X(15)

// f32 -> bf16 RNE, returned as the bf16-representable f32 (finite inputs)
__device__ __forceinline__ float bfr(float f) {
  union { float f; uint32_t i; } c; c.f = f;
  c.i = (c.i + 0x7FFFu + ((c.i >> 16) & 1u)) & 0xFFFF0000u;
  return c.f;
}

// max over a DPP lane-permutation (compile-time ctrl); key is
// (f32bits(dist)<<32)|~idx so u64 max == (max dist, min index). Exact.
template <int CTRL>
__device__ __forceinline__ unsigned long long kmax_dpp(unsigned long long k) {
  const int lo = (int)(unsigned)k;
  const int hi = (int)(unsigned)(k >> 32);
  const int plo = __builtin_amdgcn_update_dpp(lo, lo, CTRL, 0xF, 0xF, true);
  const int phi = __builtin_amdgcn_update_dpp(hi, hi, CTRL, 0xF, 0xF, true);
  const unsigned long long ok =
      ((unsigned long long)(unsigned)phi << 32) | (unsigned)plo;
  return ok > k ? ok : k;
}

__device__ __forceinline__ unsigned long long kmax_shfl(unsigned long long k, int m) {
  const int lo = __shfl_xor((int)(unsigned)k, m, 64);
  const int hi = __shfl_xor((int)(unsigned)(k >> 32), m, 64);
  const unsigned long long ok =
      ((unsigned long long)(unsigned)hi << 32) | (unsigned)lo;
  return ok > k ? ok : k;
}

// full 64-lane (maxdist, minidx) reduce:
// xor1 (quad_perm), xor2 (quad_perm), xor7 (row_half_mirror: merges quad q
// with q^1), xor15 (row_mirror: merges quad-pairs) -> each row of 16 done;
// then 16/32 crossings via ds_bpermute-based shfl.
__device__ __forceinline__ unsigned long long wave_kmax(unsigned long long k) {
  k = kmax_dpp<0xB1>(k);    // quad_perm [1,0,3,2]  == lane^1
  k = kmax_dpp<0x4E>(k);    // quad_perm [2,3,0,1]  == lane^2
  k = kmax_dpp<0x141>(k);   // row_half_mirror      == lane^7 (covers ^4)
  k = kmax_dpp<0x140>(k);   // row_mirror           == lane^15 (covers ^8)
  k = kmax_shfl(k, 16);
  k = kmax_shfl(k, 32);
  return k;
}

__global__ __attribute__((amdgpu_flat_work_group_size(THREADS_, THREADS_),
                          amdgpu_waves_per_eu(4, 4)))
void fps_kernel(const float* __restrict__ x, float* __restrict__ out)
{
#pragma clang fp contract(off)
  const int b    = blockIdx.x;
  const int t    = threadIdx.x;
  const int lane = t & 63;
  const int wave = t >> 6;

  // parity-double-buffered per-wave argmax keys: one barrier per iteration
  __shared__ unsigned long long s_key[2][NW_];

  const float* xb  = x + (size_t)b * (N_ * 3);
  float* out_x     = out;                        // [B*K*3] f32 (bf16-grid values)
  float* out_batch = out + (size_t)B_ * K_ * 3;  // [B*K]   f32 cloud ids

  // batch output (buffer re-poisoned every call -> rewrite every call)
  {
    const float bb = (float)b;
    for (int i = t; i < K_; i += THREADS_) out_batch[b * K_ + i] = bb;
  }

  // Named per-point scalars; slot i owns cloud-global index i*1024 + t
#define DECLP(i) float px##i, py##i, pz##i, m##i;
  PTS_LIST(DECLP)
#undef DECLP

#define LOADP(i) { const float* p_ = xb + 3 * ((i) * THREADS_ + t); \
                   px##i = p_[0]; py##i = p_[1]; pz##i = p_[2];     \
                   m##i = __builtin_inff(); }
  PTS_LIST(LOADP)
#undef LOADP

  // Anti-remat fence: make each loaded coord the result of an (empty) asm,
  // so the allocator cannot "spill" it by re-loading from x in the loop.
#define PINP(i) asm volatile("" : "+v"(px##i), "+v"(py##i), "+v"(pz##i));
  PTS_LIST(PINP)
#undef PINP

  // Per-point update + fused local argmax (bit-exact FMA-V1 distance)
#define UPD(i) { const float dx_ = px##i - cx;                                  \
                 const float dy_ = py##i - cy;                                  \
                 const float dz_ = pz##i - cz;                                  \
                 const float d_  = __builtin_fmaf(dz_, dz_,                     \
                                   __builtin_fmaf(dx_, dx_, dy_ * dy_));        \
                 m##i = fminf(m##i, d_);                                        \
                 if (m##i > bv) { bv = m##i; bs = (i); } }

  // ---- iteration 0: seed = point 0 ----
  float cx = xb[0], cy = xb[1], cz = xb[2];
  if (t == 0) {
    const uint64_t o = ((uint64_t)b * K_) * 3;
    out_x[o + 0] = bfr(cx); out_x[o + 1] = bfr(cy); out_x[o + 2] = bfr(cz);
  }

  float bv = -1.0f; int bs = 0;
  PTS_LIST(UPD)                      // ascending i scan keeps first index
  {
    const int bg = bs * THREADS_ + t;
    union { float f; unsigned u; } cv; cv.f = bv;
    unsigned long long key =
        ((unsigned long long)cv.u << 32) | (unsigned)~(unsigned)bg;
    key = wave_kmax(key);
    if (lane == 0) s_key[0][wave] = key;
  }
  __syncthreads();

  // ---- iterations 1..K-1 ----
  for (int j = 1; j < K_; ++j) {
    const int rp = (j - 1) & 1;
    const int wp = j & 1;

    // finalize block argmax: lanes grab the 16 per-wave keys (lane&15,
    // broadcast across lane groups), 4 DPP levels within each row of 16
    // -> every lane holds the block winner. Zero ds_bpermute.
    unsigned long long k = s_key[rp][lane & 15];
    k = kmax_dpp<0xB1>(k);
    k = kmax_dpp<0x4E>(k);
    k = kmax_dpp<0x141>(k);
    k = kmax_dpp<0x140>(k);
    const unsigned idx = ~(unsigned)k;           // winner global point index
    const int gu = __builtin_amdgcn_readfirstlane((int)idx);

    // uniform (scalar) broadcast load of the chosen point's raw coords
    cx = xb[3 * gu + 0];
    cy = xb[3 * gu + 1];
    cz = xb[3 * gu + 2];
    if (t == 0) {
      const uint64_t o = ((uint64_t)b * K_ + j) * 3;
      out_x[o + 0] = bfr(cx); out_x[o + 1] = bfr(cy); out_x[o + 2] = bfr(cz);
    }

    // update mind + fused local argmax for next round
    bv = -1.0f; bs = 0;
    PTS_LIST(UPD)
    {
      const int bg = bs * THREADS_ + t;
      union { float f; unsigned u; } cv; cv.f = bv;
      unsigned long long key =
          ((unsigned long long)cv.u << 32) | (unsigned)~(unsigned)bg;
      key = wave_kmax(key);
      if (lane == 0) s_key[wp][wave] = key;
    }
    __syncthreads();
  }
#undef UPD
}

extern "C" void kernel_launch(void* const* d_in, const int* in_sizes, int n_in,
                              void* d_out, int out_size, void* d_ws, size_t ws_size,
                              hipStream_t stream) {
  const float* x = (const float*)d_in[0];  // f32, [B*N, 3]
  float* out     = (float*)d_out;          // f32: [B*K*3] coords + [B*K] batch
  (void)in_sizes; (void)n_in; (void)out_size; (void)d_ws; (void)ws_size;
  hipLaunchKernelGGL(fps_kernel, dim3(B_), dim3(THREADS_), 0, stream, x, out);
}

// Round 5
// 5758.067 us; speedup vs baseline: 13.3602x; 1.0119x over previous
//
#include <hip/hip_runtime.h>
#include <cstdint>

// Reference semantics (validated, absmax=0.0 — DO NOT change arithmetic):
//  - selection on RAW f32 coords, distance = fma(dz,dz, fma(dx,dx, dy*dy))
//    with dx/dy/dz plain f32 subs;
//  - min/argmax exact, FIRST-index tie-break (min global point index);
//  - output coords bf16-RNE-rounded, batch = float b.
//
// R16: R15's pre-loop asm pin FAILED to force residency (VGPR_Count stayed
// 52) — a one-shot pin lets the allocator spill right after it and reload
// from scratch every iteration (invisible in FETCH_SIZE: scratch hits L2).
// Fix: pin ALL 64 loop-state values (px,py,pz,m x16) INSIDE the K-loop —
// now spill+reload costs 2 mem ops per value per iteration vs 0 for staying
// live; budget is 128 VGPR at the mandatory 4 waves/EU (1024-thr block).
// Also: per-point argmax scan (cmp+2 cndmask = 3/pt) replaced by v_max3
// tree (8 instr) + descending equality/cndmask index chain (2/pt) — exact:
// same max value over the same finite set; descending evaluation => smallest
// matching slot wins (= first-index tie-break). DPP wave/block reduction
// kept from R15 (validated, -2.4 ms).
#pragma clang fp contract(off)

#define B_ 16
#define N_ 16384
#define K_ 4096
#define THREADS_ 1024
#define PTS_ (N_ / THREADS_)   // 16 points per thread
#define NW_ (THREADS_ / 64)    // 16 waves per block

#define PTS_LIST(X) \
  X(0) X(1) X(2) X(3) X(4) X(5) X(6) X(7) \
  X(8) X(9) X(10) X(11) X(12) X(13) X(14) X(15)

// f32 -> bf16 RNE, returned as the bf16-representable f32 (finite inputs)
__device__ __forceinline__ float bfr(float f) {
  union { float f; uint32_t i; } c; c.f = f;
  c.i = (c.i + 0x7FFFu + ((c.i >> 16) & 1u)) & 0xFFFF0000u;
  return c.f;
}

// max over a DPP lane-permutation (compile-time ctrl); key is
// (f32bits(dist)<<32)|~idx so u64 max == (max dist, min index). Exact.
template <int CTRL>
__device__ __forceinline__ unsigned long long kmax_dpp(unsigned long long k) {
  const int lo = (int)(unsigned)k;
  const int hi = (int)(unsigned)(k >> 32);
  const int plo = __builtin_amdgcn_update_dpp(lo, lo, CTRL, 0xF, 0xF, true);
  const int phi = __builtin_amdgcn_update_dpp(hi, hi, CTRL, 0xF, 0xF, true);
  const unsigned long long ok =
      ((unsigned long long)(unsigned)phi << 32) | (unsigned)plo;
  return ok > k ? ok : k;
}

__device__ __forceinline__ unsigned long long kmax_shfl(unsigned long long k, int m) {
  const int lo = __shfl_xor((int)(unsigned)k, m, 64);
  const int hi = __shfl_xor((int)(unsigned)(k >> 32), m, 64);
  const unsigned long long ok =
      ((unsigned long long)(unsigned)hi << 32) | (unsigned)lo;
  return ok > k ? ok : k;
}

// full 64-lane (maxdist, minidx) reduce: 4 DPP levels + 2 bpermute levels
__device__ __forceinline__ unsigned long long wave_kmax(unsigned long long k) {
  k = kmax_dpp<0xB1>(k);    // quad_perm [1,0,3,2]  == lane^1
  k = kmax_dpp<0x4E>(k);    // quad_perm [2,3,0,1]  == lane^2
  k = kmax_dpp<0x141>(k);   // row_half_mirror      == lane^7 (covers ^4)
  k = kmax_dpp<0x140>(k);   // row_mirror           == lane^15 (covers ^8)
  k = kmax_shfl(k, 16);
  k = kmax_shfl(k, 32);
  return k;
}

__global__ __attribute__((amdgpu_flat_work_group_size(THREADS_, THREADS_),
                          amdgpu_waves_per_eu(4, 4)))
void fps_kernel(const float* __restrict__ x, float* __restrict__ out)
{
#pragma clang fp contract(off)
  const int b    = blockIdx.x;
  const int t    = threadIdx.x;
  const int lane = t & 63;
  const int wave = t >> 6;

  // parity-double-buffered per-wave argmax keys: one barrier per iteration
  __shared__ unsigned long long s_key[2][NW_];

  const float* xb  = x + (size_t)b * (N_ * 3);
  float* out_x     = out;                        // [B*K*3] f32 (bf16-grid values)
  float* out_batch = out + (size_t)B_ * K_ * 3;  // [B*K]   f32 cloud ids

  // batch output (buffer re-poisoned every call -> rewrite every call)
  {
    const float bb = (float)b;
    for (int i = t; i < K_; i += THREADS_) out_batch[b * K_ + i] = bb;
  }

  // Named per-point scalars; slot i owns cloud-global index i*1024 + t
#define DECLP(i) float px##i, py##i, pz##i, m##i;
  PTS_LIST(DECLP)
#undef DECLP

#define LOADP(i) { const float* p_ = xb + 3 * ((i) * THREADS_ + t); \
                   px##i = p_[0]; py##i = p_[1]; pz##i = p_[2];     \
                   m##i = __builtin_inff(); }
  PTS_LIST(LOADP)
#undef LOADP

  // In-loop anti-spill pin: forces all 64 loop-state values to be VGPR-
  // resident at every iteration; spilling would cost reload+store per iter.
#define PINP(i) asm volatile("" : "+v"(px##i), "+v"(py##i), "+v"(pz##i), "+v"(m##i));

  // dist update (bit-exact FMA-V1), min into m##i
#define UPD(i) { const float dx_ = px##i - cx;                                  \
                 const float dy_ = py##i - cy;                                  \
                 const float dz_ = pz##i - cz;                                  \
                 const float d_  = __builtin_fmaf(dz_, dz_,                     \
                                   __builtin_fmaf(dx_, dx_, dy_ * dy_));        \
                 m##i = fminf(m##i, d_); }

  // max3 tree over the 16 m values (fmaxf nests fuse to v_max3_f32); value
  // identical to the sequential scan's max (same finite set).
#define MAXTREE(M_) { const float t0_ = fmaxf(fmaxf(m0,  m1),  m2);  \
                      const float t1_ = fmaxf(fmaxf(m3,  m4),  m5);  \
                      const float t2_ = fmaxf(fmaxf(m6,  m7),  m8);  \
                      const float t3_ = fmaxf(fmaxf(m9,  m10), m11); \
                      const float t4_ = fmaxf(fmaxf(m12, m13), m14); \
                      const float u0_ = fmaxf(fmaxf(t0_, t1_), t2_); \
                      const float u1_ = fmaxf(fmaxf(t3_, t4_), m15); \
                      M_ = fmaxf(u0_, u1_); }

  // descending equality chain: final bs = smallest slot with m==M
#define IDXCHAIN(M_, BS_) { BS_ = 15;                                \
      if (m14 == M_) BS_ = 14; if (m13 == M_) BS_ = 13;              \
      if (m12 == M_) BS_ = 12; if (m11 == M_) BS_ = 11;              \
      if (m10 == M_) BS_ = 10; if (m9  == M_) BS_ = 9;               \
      if (m8  == M_) BS_ = 8;  if (m7  == M_) BS_ = 7;               \
      if (m6  == M_) BS_ = 6;  if (m5  == M_) BS_ = 5;               \
      if (m4  == M_) BS_ = 4;  if (m3  == M_) BS_ = 3;               \
      if (m2  == M_) BS_ = 2;  if (m1  == M_) BS_ = 1;               \
      if (m0  == M_) BS_ = 0; }

  // ---- iteration 0: seed = point 0 ----
  float cx = xb[0], cy = xb[1], cz = xb[2];
  if (t == 0) {
    const uint64_t o = ((uint64_t)b * K_) * 3;
    out_x[o + 0] = bfr(cx); out_x[o + 1] = bfr(cy); out_x[o + 2] = bfr(cz);
  }

  {
    PTS_LIST(UPD)                    // m_i = d_i (min with +inf)
    float bv; int bs;
    MAXTREE(bv)
    IDXCHAIN(bv, bs)
    const int bg = bs * THREADS_ + t;
    union { float f; unsigned u; } cv; cv.f = bv;
    unsigned long long key =
        ((unsigned long long)cv.u << 32) | (unsigned)~(unsigned)bg;
    key = wave_kmax(key);
    if (lane == 0) s_key[0][wave] = key;
  }
  __syncthreads();

  // ---- iterations 1..K-1 ----
  for (int j = 1; j < K_; ++j) {
    const int rp = (j - 1) & 1;
    const int wp = j & 1;

    // pin loop state in registers for this iteration
    PTS_LIST(PINP)

    // finalize block argmax: 16 per-wave keys broadcast (lane&15), 4 DPP
    // levels within each 16-lane row -> every lane holds the block winner.
    unsigned long long k = s_key[rp][lane & 15];
    k = kmax_dpp<0xB1>(k);
    k = kmax_dpp<0x4E>(k);
    k = kmax_dpp<0x141>(k);
    k = kmax_dpp<0x140>(k);
    const unsigned idx = ~(unsigned)k;           // winner global point index
    const int gu = __builtin_amdgcn_readfirstlane((int)idx);

    // uniform (scalar) broadcast load of the chosen point's raw coords
    cx = xb[3 * gu + 0];
    cy = xb[3 * gu + 1];
    cz = xb[3 * gu + 2];
    if (t == 0) {
      const uint64_t o = ((uint64_t)b * K_ + j) * 3;
      out_x[o + 0] = bfr(cx); out_x[o + 1] = bfr(cy); out_x[o + 2] = bfr(cz);
    }

    // update mind + tree argmax for next round
    PTS_LIST(UPD)
    {
      float bv; int bs;
      MAXTREE(bv)
      IDXCHAIN(bv, bs)
      const int bg = bs * THREADS_ + t;
      union { float f; unsigned u; } cv; cv.f = bv;
      unsigned long long key =
          ((unsigned long long)cv.u << 32) | (unsigned)~(unsigned)bg;
      key = wave_kmax(key);
      if (lane == 0) s_key[wp][wave] = key;
    }
    __syncthreads();
  }
#undef UPD
#undef PINP
#undef MAXTREE
#undef IDXCHAIN

}

extern "C" void kernel_launch(void* const* d_in, const int* in_sizes, int n_in,
                              void* d_out, int out_size, void* d_ws, size_t ws_size,
                              hipStream_t stream) {
  const float* x = (const float*)d_in[0];  // f32, [B*N, 3]
  float* out     = (float*)d_out;          // f32: [B*K*3] coords + [B*K] batch
  (void)in_sizes; (void)n_in; (void)out_size; (void)d_ws; (void)ws_size;
  hipLaunchKernelGGL(fps_kernel, dim3(B_), dim3(THREADS_), 0, stream, x, out);
}

// Round 8
// 5461.168 us; speedup vs baseline: 14.0865x; 1.0544x over previous
//
#include <hip/hip_runtime.h>
#include <cstdint>

// Reference semantics (validated, absmax=0.0 — DO NOT change arithmetic):
//  - selection on RAW f32 coords, distance = fma(dz,dz, fma(dx,dx, dy*dy))
//    with dx/dy/dz plain f32 subs;
//  - min/argmax exact, FIRST-index tie-break (min global point index);
//  - output coords bf16-RNE-rounded, batch = float b.
//
// R19 = R18 with the compile fix (update_dpp ctrl must be a constant ->
// template parameter). R18 rationale:
// VALUBusy 6.45% / 6.25% active-CU fraction => active CUs' VALU pipe is
// SATURATED: time == VALU instruction count (~420/thread/iter vs ~240
// essential; overhead = remat reload address calc + issue). Fix: stop
// fighting the allocator —
//  1) x,y live in LDS (float2 s_xy[16384], 128 KB): per-iter reads are
//     ds_read_b64 with IMMEDIATE offsets (zero VALU), on the DS pipe
//     (hidden under VALU); lanes 8B apart -> 2-way bank alias = free.
//     z,m stay in 32 named regs (the allocator historically keeps these).
//  2) wave argmax: 6-step DPP prefix+bcast f32-max (identity 0; all m>=0)
//     + readlane63, then u32-min DPP of (bv==max ? bg : ~0) for the
//     min-index tie-break — exact same (max dist, min index) lattice.
//  3) center cx,cy from LDS (uniform broadcast read), cz from global
//     (hidden under cz-independent dx/dy VALU).
// Block finalize (u64 key DPP butterfly) and max3-tree/idx-chain kept
// from R15/R16 (validated). No inline asm, no volatile, no pins.
#pragma clang fp contract(off)

#define B_ 16
#define N_ 16384
#define K_ 4096
#define THREADS_ 1024
#define PTS_ (N_ / THREADS_)   // 16 points per thread
#define NW_ (THREADS_ / 64)    // 16 waves per block

#define PTS_LIST(X) \
  X(0) X(1) X(2) X(3) X(4) X(5) X(6) X(7) \
  X(8) X(9) X(10) X(11) X(12) X(13) X(14) X(15)

// f32 -> bf16 RNE, returned as the bf16-representable f32 (finite inputs)
__device__ __forceinline__ float bfr(float f) {
  union { float f; uint32_t i; } c; c.f = f;
  c.i = (c.i + 0x7FFFu + ((c.i >> 16) & 1u)) & 0xFFFF0000u;
  return c.f;
}

// ---- DPP helpers (ctrl must be compile-time constant -> template) ----------
// fmax with a DPP-permuted copy; invalid-source lanes contribute 0
// (identity: all reduced values are >= 0).
template <int CTRL>
__device__ __forceinline__ float dpp_fmax(float v) {
  union { float f; int i; } s, p;
  s.f = v;
  p.i = __builtin_amdgcn_update_dpp(0, s.i, CTRL, 0xF, 0xF, false);
  return fmaxf(v, p.f);
}
// u32 min with a DPP-permuted copy; invalid-source lanes contribute ~0u.
template <int CTRL>
__device__ __forceinline__ unsigned dpp_umin(unsigned v) {
  const int p = __builtin_amdgcn_update_dpp((int)0xFFFFFFFFu, (int)v,
                                            CTRL, 0xF, 0xF, false);
  const unsigned pu = (unsigned)p;
  return pu < v ? pu : v;
}

// wave-wide (max bv, min bg among maxed) -> (wv, wg), uniform in all lanes.
// Classic GCN 6-step: row_shr 1/2/4/8 (prefix within rows of 16) then
// row_bcast:15, row_bcast:31 -> lane 63 holds the full-wave result.
__device__ __forceinline__ void wave_argmax(float bv, unsigned bg,
                                            float& wv, unsigned& wg) {
  float v = bv;
  v = dpp_fmax<0x111>(v);  // row_shr:1
  v = dpp_fmax<0x112>(v);  // row_shr:2
  v = dpp_fmax<0x114>(v);  // row_shr:4
  v = dpp_fmax<0x118>(v);  // row_shr:8
  v = dpp_fmax<0x142>(v);  // row_bcast:15
  v = dpp_fmax<0x143>(v);  // row_bcast:31
  union { float f; int i; } mx;
  mx.i = __builtin_amdgcn_readlane(__builtin_bit_cast(int, v), 63);
  unsigned c = (bv == mx.f) ? bg : 0xFFFFFFFFu;
  c = dpp_umin<0x111>(c);
  c = dpp_umin<0x112>(c);
  c = dpp_umin<0x114>(c);
  c = dpp_umin<0x118>(c);
  c = dpp_umin<0x142>(c);
  c = dpp_umin<0x143>(c);
  wg = (unsigned)__builtin_amdgcn_readlane((int)c, 63);
  wv = mx.f;
}

// u64 key max over a DPP lane-permutation (block-finalize butterfly; key is
// (f32bits(dist)<<32)|~idx so u64 max == (max dist, min index)). Exact.
template <int CTRL>
__device__ __forceinline__ unsigned long long kmax_dpp(unsigned long long k) {
  const int lo = (int)(unsigned)k;
  const int hi = (int)(unsigned)(k >> 32);
  const int plo = __builtin_amdgcn_update_dpp(lo, lo, CTRL, 0xF, 0xF, true);
  const int phi = __builtin_amdgcn_update_dpp(hi, hi, CTRL, 0xF, 0xF, true);
  const unsigned long long ok =
      ((unsigned long long)(unsigned)phi << 32) | (unsigned)plo;
  return ok > k ? ok : k;
}

__global__ __attribute__((amdgpu_flat_work_group_size(THREADS_, THREADS_),
                          amdgpu_waves_per_eu(4, 4)))
void fps_kernel(const float* __restrict__ x, float* __restrict__ out)
{
#pragma clang fp contract(off)
  const int b    = blockIdx.x;
  const int t    = threadIdx.x;
  const int lane = t & 63;
  const int wave = t >> 6;

  // x,y of all 16384 points (128 KB). Thread t reads only slots {i*1024+t}
  // in the update loop (immediate-offset ds_read_b64); center reads are
  // uniform-address broadcasts. Written once at init.
  __shared__ float2 s_xy[N_];
  // parity-double-buffered per-wave argmax keys: one barrier per iteration
  __shared__ unsigned long long s_key[2][NW_];

  const float* xb  = x + (size_t)b * (N_ * 3);
  float* out_x     = out;                        // [B*K*3] f32 (bf16-grid values)
  float* out_batch = out + (size_t)B_ * K_ * 3;  // [B*K]   f32 cloud ids

  // batch output (buffer re-poisoned every call -> rewrite every call)
  {
    const float bb = (float)b;
    for (int i = t; i < K_; i += THREADS_) out_batch[b * K_ + i] = bb;
  }

  // z and running-min in named registers; x,y staged to LDS
#define DECLP(i) float pz##i, m##i;
  PTS_LIST(DECLP)
#undef DECLP

#define LOADP(i) { const float* p_ = xb + 3 * ((i) * THREADS_ + t); \
                   float2 v_; v_.x = p_[0]; v_.y = p_[1];           \
                   s_xy[(i) * THREADS_ + t] = v_;                   \
                   pz##i = p_[2]; m##i = __builtin_inff(); }
  PTS_LIST(LOADP)
#undef LOADP

  // dist update (bit-exact FMA-V1), min into m##i; x,y from LDS (same bits)
#define UPD(i) { const float2 v_ = s_xy[(i) * THREADS_ + t];                    \
                 const float dx_ = v_.x - cx;                                   \
                 const float dy_ = v_.y - cy;                                   \
                 const float dz_ = pz##i - cz;                                  \
                 const float d_  = __builtin_fmaf(dz_, dz_,                     \
                                   __builtin_fmaf(dx_, dx_, dy_ * dy_));        \
                 m##i = fminf(m##i, d_); }

  // max3 tree over the 16 m values (fmaxf nests fuse to v_max3_f32); value
  // identical to the sequential scan's max (same finite set).
#define MAXTREE(M_) { const float t0_ = fmaxf(fmaxf(m0,  m1),  m2);  \
                      const float t1_ = fmaxf(fmaxf(m3,  m4),  m5);  \
                      const float t2_ = fmaxf(fmaxf(m6,  m7),  m8);  \
                      const float t3_ = fmaxf(fmaxf(m9,  m10), m11); \
                      const float t4_ = fmaxf(fmaxf(m12, m13), m14); \
                      const float u0_ = fmaxf(fmaxf(t0_, t1_), t2_); \
                      const float u1_ = fmaxf(fmaxf(t3_, t4_), m15); \
                      M_ = fmaxf(u0_, u1_); }

  // descending equality chain: final bs = smallest slot with m==M
#define IDXCHAIN(M_, BS_) { BS_ = 15;                                \
      if (m14 == M_) BS_ = 14; if (m13 == M_) BS_ = 13;              \
      if (m12 == M_) BS_ = 12; if (m11 == M_) BS_ = 11;              \
      if (m10 == M_) BS_ = 10; if (m9  == M_) BS_ = 9;               \
      if (m8  == M_) BS_ = 8;  if (m7  == M_) BS_ = 7;               \
      if (m6  == M_) BS_ = 6;  if (m5  == M_) BS_ = 5;               \
      if (m4  == M_) BS_ = 4;  if (m3  == M_) BS_ = 3;               \
      if (m2  == M_) BS_ = 2;  if (m1  == M_) BS_ = 1;               \
      if (m0  == M_) BS_ = 0; }

  // per-thread argmax -> wave argmax -> per-wave key in LDS
#define REDUCE_AND_POST(PARITY) {                                        \
      float bv; int bs;                                                  \
      MAXTREE(bv)                                                        \
      IDXCHAIN(bv, bs)                                                   \
      const unsigned bg = (unsigned)(bs * THREADS_ + t);                 \
      float wv; unsigned wg;                                             \
      wave_argmax(bv, bg, wv, wg);                                       \
      if (lane == 0) {                                                   \
        union { float f; unsigned u; } cv; cv.f = wv;                    \
        s_key[PARITY][wave] =                                            \
            ((unsigned long long)cv.u << 32) | (unsigned)~wg;            \
      } }

  // ---- iteration 0: seed = point 0 ----
  float cx = xb[0], cy = xb[1], cz = xb[2];
  if (t == 0) {
    const uint64_t o = ((uint64_t)b * K_) * 3;
    out_x[o + 0] = bfr(cx); out_x[o + 1] = bfr(cy); out_x[o + 2] = bfr(cz);
  }

  PTS_LIST(UPD)                      // m_i = d_i (min with +inf)
  REDUCE_AND_POST(0)
  __syncthreads();

  // ---- iterations 1..K-1 ----
  for (int j = 1; j < K_; ++j) {
    const int rp = (j - 1) & 1;
    const int wp = j & 1;

    // finalize block argmax: 16 per-wave keys broadcast (lane&15), 4 DPP
    // levels within each 16-lane row -> every lane holds the block winner.
    unsigned long long k = s_key[rp][lane & 15];
    k = kmax_dpp<0xB1>(k);    // quad_perm lane^1
    k = kmax_dpp<0x4E>(k);    // quad_perm lane^2
    k = kmax_dpp<0x141>(k);   // row_half_mirror (lane^7, covers ^4)
    k = kmax_dpp<0x140>(k);   // row_mirror (lane^15, covers ^8)
    const unsigned idx = ~(unsigned)k;           // winner global point index
    const int gu = __builtin_amdgcn_readfirstlane((int)idx);

    // center: x,y from LDS (uniform broadcast read), z from global (its
    // ~200cy L2 latency hides under the cz-independent dx/dy VALU below)
    const float2 cxy = s_xy[gu];
    cx = cxy.x; cy = cxy.y;
    cz = xb[3 * gu + 2];
    if (t == 0) {
      const uint64_t o = ((uint64_t)b * K_ + j) * 3;
      out_x[o + 0] = bfr(cx); out_x[o + 1] = bfr(cy); out_x[o + 2] = bfr(cz);
    }

    // update mind + per-thread/wave argmax for next round
    PTS_LIST(UPD)
    REDUCE_AND_POST(wp)
    __syncthreads();
  }
#undef UPD
#undef MAXTREE
#undef IDXCHAIN
#undef REDUCE_AND_POST

}

extern "C" void kernel_launch(void* const* d_in, const int* in_sizes, int n_in,
                              void* d_out, int out_size, void* d_ws, size_t ws_size,
                              hipStream_t stream) {
  const float* x = (const float*)d_in[0];  // f32, [B*N, 3]
  float* out     = (float*)d_out;          // f32: [B*K*3] coords + [B*K] batch
  (void)in_sizes; (void)n_in; (void)out_size; (void)d_ws; (void)ws_size;
  hipLaunchKernelGGL(fps_kernel, dim3(B_), dim3(THREADS_), 0, stream, x, out);
}